// Round 1
// baseline (3465.800 us; speedup 1.0000x reference)
//
#include <hip/hip_runtime.h>
#include <hip/hip_bf16.h>
#include <math.h>

#define N_ATOMS 500000
#define NODE 128
#define EDGE 16
#define OUT 128
#define KTOT 272            // 128 (a_sum) + 16 (b_sum) + 128 (self)
#define NBLK 1024           // total blocks in fused kernel 1
#define B1 102
#define B2 307
#define B3 410
#define B4 205
#define EPS 1e-5f

// ---------------------------------------------------------------------------
// Kernel 1: gather + dense 272->128 dot + scatter + per-block BN partials.
// Block = 512 threads = 4 groups of 128 (thread within group = out channel).
// LDS: Wc[272][128] fp32 (W_d rows 0..143, W_self rows 144..271), bias, inputs.
// ---------------------------------------------------------------------------
__global__ __launch_bounds__(512, 1) void gdc_fused(
    const float* __restrict__ atom, const float* __restrict__ bond,
    const int* __restrict__ a1, const int* __restrict__ b1,
    const int* __restrict__ a2, const int* __restrict__ b2,
    const int* __restrict__ a3, const int* __restrict__ b3,
    const int* __restrict__ a4, const int* __restrict__ b4,
    const float* __restrict__ W1, const float* __restrict__ W2,
    const float* __restrict__ W3, const float* __restrict__ W4,
    const float* __restrict__ Wself, const float* __restrict__ bias,
    float* __restrict__ out,
    float* __restrict__ sumPart, float* __restrict__ sqPart)
{
    __shared__ float Wc[KTOT * 128];      // 139264 B
    __shared__ float inb[4][KTOT];        // 4352 B
    __shared__ float bias_s[128];         // 512 B
    __shared__ float red[512];            // 2048 B

    const int blk = blockIdx.x;
    int deg, n, lb, nb;
    const int* aidx; const int* bidx; const float* Wd;
    if (blk < B1)            { deg = 1; n =  50000; lb = blk;            nb = B1; aidx = a1; bidx = b1; Wd = W1; }
    else if (blk < B1+B2)    { deg = 2; n = 150000; lb = blk-B1;         nb = B2; aidx = a2; bidx = b2; Wd = W2; }
    else if (blk < B1+B2+B3) { deg = 3; n = 200000; lb = blk-(B1+B2);    nb = B3; aidx = a3; bidx = b3; Wd = W3; }
    else                     { deg = 4; n = 100000; lb = blk-(B1+B2+B3); nb = B4; aidx = a4; bidx = b4; Wd = W4; }

    const int tid = threadIdx.x;

    // Stage weights into LDS (float4 copies; counts divisible by 4).
    {
        const float4* src = (const float4*)Wd;
        float4* dst = (float4*)Wc;
        for (int idx = tid; idx < (144*128)/4; idx += 512) dst[idx] = src[idx];
        const float4* src2 = (const float4*)Wself;
        float4* dst2 = (float4*)(Wc + 144*128);
        for (int idx = tid; idx < (128*128)/4; idx += 512) dst2[idx] = src2[idx];
        if (tid < 128) bias_s[tid] = bias[tid];
    }
    __syncthreads();

    const int g = tid >> 7;        // group 0..3
    const int t = tid & 127;       // out channel
    float psum = 0.f, psq = 0.f;

    const int per_iter = 4 * nb;
    const int iters = (n + per_iter - 1) / per_iter;

    for (int it = 0; it < iters; ++it) {
        const int i = (it * nb + lb) * 4 + g;
        const bool active = (i < n);
        int own = 0;
        if (active) {
            const int* ar = aidx + (size_t)i * (deg + 1);
            own = ar[0];
            const float s0 = atom[(size_t)own * 128 + t];
            float asum = s0;
            for (int j = 1; j <= deg; ++j)
                asum += atom[(size_t)ar[j] * 128 + t];
            inb[g][t] = asum;
            inb[g][144 + t] = s0;
            if (t < 16) {
                const int* br = bidx + (size_t)i * deg;
                float bs = 0.f;
                for (int j = 0; j < deg; ++j)
                    bs += bond[(size_t)br[j] * 16 + t];
                inb[g][128 + t] = bs;
            }
        }
        __syncthreads();
        if (active) {
            float acc = bias_s[t];
            #pragma unroll 8
            for (int k = 0; k < KTOT; ++k)
                acc = fmaf(inb[g][k], Wc[k * 128 + t], acc);
            out[(size_t)own * 128 + t] = acc;
            psum += acc;
            psq  += acc * acc;
        }
        __syncthreads();
    }

    // Deterministic per-block partial reduction across the 4 groups.
    red[tid] = psum;
    __syncthreads();
    if (tid < 128)
        sumPart[(size_t)blk * 128 + tid] = red[tid] + red[tid+128] + red[tid+256] + red[tid+384];
    __syncthreads();
    red[tid] = psq;
    __syncthreads();
    if (tid < 128)
        sqPart[(size_t)blk * 128 + tid]  = red[tid] + red[tid+128] + red[tid+256] + red[tid+384];
}

// ---------------------------------------------------------------------------
// Kernel 2: reduce 1024 partials per channel -> mean, invstd (deterministic).
// Grid: 128 blocks (one per channel) x 256 threads.
// ---------------------------------------------------------------------------
__global__ void gdc_stats(const float* __restrict__ sumPart,
                          const float* __restrict__ sqPart,
                          float* __restrict__ mv)
{
    const int c = blockIdx.x;
    const int j = threadIdx.x;
    __shared__ float rs[256], rq[256];
    float s = 0.f, q = 0.f;
    for (int b = j; b < NBLK; b += 256) {
        s += sumPart[(size_t)b * 128 + c];
        q += sqPart[(size_t)b * 128 + c];
    }
    rs[j] = s; rq[j] = q;
    __syncthreads();
    for (int off = 128; off > 0; off >>= 1) {
        if (j < off) { rs[j] += rs[j + off]; rq[j] += rq[j + off]; }
        __syncthreads();
    }
    if (j == 0) {
        const float mean = rs[0] / (float)N_ATOMS;
        const float var  = rq[0] / (float)N_ATOMS - mean * mean;
        mv[c]       = mean;
        mv[128 + c] = rsqrtf(var + EPS);
    }
}

// ---------------------------------------------------------------------------
// Kernel 3: in-place normalize + ReLU on d_out. float4; per-thread channel
// is loop-invariant (grid stride in floats is a multiple of 128).
// ---------------------------------------------------------------------------
__global__ __launch_bounds__(256) void gdc_norm(float* __restrict__ out,
                                                const float* __restrict__ mv)
{
    const size_t total4 = (size_t)N_ATOMS * 128 / 4;
    size_t idx = (size_t)blockIdx.x * 256 + threadIdx.x;
    const int c = (int)((idx * 4) & 127);
    const float4 m = *(const float4*)(mv + c);
    const float4 iv = *(const float4*)(mv + 128 + c);
    const size_t stride = (size_t)gridDim.x * 256;
    for (; idx < total4; idx += stride) {
        float4 v = ((float4*)out)[idx];
        v.x = fmaxf(0.f, (v.x - m.x) * iv.x);
        v.y = fmaxf(0.f, (v.y - m.y) * iv.y);
        v.z = fmaxf(0.f, (v.z - m.z) * iv.z);
        v.w = fmaxf(0.f, (v.w - m.w) * iv.w);
        ((float4*)out)[idx] = v;
    }
}

extern "C" void kernel_launch(void* const* d_in, const int* in_sizes, int n_in,
                              void* d_out, int out_size, void* d_ws, size_t ws_size,
                              hipStream_t stream) {
    // setup_inputs() dict order:
    const float* atom  = (const float*)d_in[0];
    const float* bond  = (const float*)d_in[1];
    const int*   a1    = (const int*)d_in[2];
    const int*   b1    = (const int*)d_in[3];
    const int*   a2    = (const int*)d_in[4];
    const int*   b2    = (const int*)d_in[5];
    const int*   a3    = (const int*)d_in[6];
    const int*   b3    = (const int*)d_in[7];
    const int*   a4    = (const int*)d_in[8];
    const int*   b4    = (const int*)d_in[9];
    const float* Wself = (const float*)d_in[10];
    const float* W1    = (const float*)d_in[11];
    const float* W2    = (const float*)d_in[12];
    const float* W3    = (const float*)d_in[13];
    const float* W4    = (const float*)d_in[14];
    const float* bias  = (const float*)d_in[15];
    float* out = (float*)d_out;

    // ws layout: sumPart[1024*128] | sqPart[1024*128] | mv[256]
    float* sumPart = (float*)d_ws;
    float* sqPart  = sumPart + (size_t)NBLK * 128;
    float* mv      = sqPart + (size_t)NBLK * 128;

    hipLaunchKernelGGL(gdc_fused, dim3(NBLK), dim3(512), 0, stream,
                       atom, bond, a1, b1, a2, b2, a3, b3, a4, b4,
                       W1, W2, W3, W4, Wself, bias, out, sumPart, sqPart);
    hipLaunchKernelGGL(gdc_stats, dim3(128), dim3(256), 0, stream,
                       sumPart, sqPart, mv);
    hipLaunchKernelGGL(gdc_norm, dim3(2048), dim3(256), 0, stream, out, mv);
}

// Round 2
// 472.894 us; speedup vs baseline: 7.3289x; 7.3289x over previous
//
#include <hip/hip_runtime.h>
#include <hip/hip_bf16.h>
#include <math.h>

#define N_ATOMS 500000
#define EPS 1e-5f
#define LDA 296   // bf16 elems per A_lds row: 288 + 8 pad (breaks bank aliasing)

// blocks per degree segment, sized so each block gathers ~3800 atom rows
#define NB1 27
#define NB2 118
#define NB3 209
#define NB4 131
#define TOTB (NB1 + NB2 + NB3 + NB4)   // 485

typedef __attribute__((ext_vector_type(8))) short short8;
typedef __attribute__((ext_vector_type(4))) float floatx4;

__device__ __forceinline__ unsigned short f2bf(float f) {
    unsigned int x = __float_as_uint(f);
    x += 0x7FFF + ((x >> 16) & 1);          // round-to-nearest-even
    return (unsigned short)(x >> 16);
}

__device__ __forceinline__ float4 add4(float4 a, float4 b) {
    return make_float4(a.x + b.x, a.y + b.y, a.z + b.z, a.w + b.w);
}

__device__ __forceinline__ void st_bf4(unsigned short* p, float4 v) {
    ushort4 u;
    u.x = f2bf(v.x); u.y = f2bf(v.y); u.z = f2bf(v.z); u.w = f2bf(v.w);
    *reinterpret_cast<ushort4*>(p) = u;     // ds_write_b64
}

// ---------------------------------------------------------------------------
// Fused: gather -> bf16 pack -> MFMA (64x288 @ 288x128) -> scatter + BN partials
// 256 threads = 4 waves. Wave w owns output cols [32w, 32w+32).
// B (weights) live in registers: 9 ksteps x 2 ntiles x short8 = 72 VGPR/lane.
// ---------------------------------------------------------------------------
__global__ __launch_bounds__(256, 2) void gdc_mfma(
    const float* __restrict__ atom, const float* __restrict__ bond,
    const int* __restrict__ a1, const int* __restrict__ b1,
    const int* __restrict__ a2, const int* __restrict__ b2,
    const int* __restrict__ a3, const int* __restrict__ b3,
    const int* __restrict__ a4, const int* __restrict__ b4,
    const float* __restrict__ W1, const float* __restrict__ W2,
    const float* __restrict__ W3, const float* __restrict__ W4,
    const float* __restrict__ Wself, const float* __restrict__ bias,
    float* __restrict__ out,
    float* __restrict__ sumPart, float* __restrict__ sqPart)
{
    __shared__ __align__(16) unsigned short A[64 * LDA];   // 37888 B
    __shared__ int own_lds[64];

    const int blk = blockIdx.x;
    int deg, n, lb, nb;
    const int* aidx; const int* bidx; const float* Wd;
    if (blk < NB1)                 { deg = 1; n =  50000; lb = blk;                  nb = NB1; aidx = a1; bidx = b1; Wd = W1; }
    else if (blk < NB1+NB2)        { deg = 2; n = 150000; lb = blk-NB1;              nb = NB2; aidx = a2; bidx = b2; Wd = W2; }
    else if (blk < NB1+NB2+NB3)    { deg = 3; n = 200000; lb = blk-(NB1+NB2);        nb = NB3; aidx = a3; bidx = b3; Wd = W3; }
    else                           { deg = 4; n = 100000; lb = blk-(NB1+NB2+NB3);    nb = NB4; aidx = a4; bidx = b4; Wd = W4; }

    const int tid  = threadIdx.x;
    const int lane = tid & 63;
    const int wv   = tid >> 6;          // 0..3
    const int nbase = wv * 32;
    const int lrow  = lane & 15;        // A row / B,C col within 16-tile
    const int lkhi  = lane >> 4;        // 0..3

    // ---- B fragments in registers (once per block). k layout: [W_d(0..143) | W_self(144..271) | 0 pad]
    short8 bfr[9][2];
    #pragma unroll
    for (int ks = 0; ks < 9; ++ks) {
        #pragma unroll
        for (int nt = 0; nt < 2; ++nt) {
            const int col = nbase + nt * 16 + lrow;
            #pragma unroll
            for (int j = 0; j < 8; ++j) {
                const int k = ks * 32 + (lkhi << 3) + j;
                float w = 0.f;
                if (k < 144)      w = Wd[k * 128 + col];
                else if (k < 272) w = Wself[(k - 144) * 128 + col];
                bfr[ks][nt][j] = (short)f2bf(w);
            }
        }
    }
    float bias_r[2];
    bias_r[0] = bias[nbase + lrow];
    bias_r[1] = bias[nbase + 16 + lrow];

    // zero K-pad cols 272..287 for all 64 rows (stays zero forever)
    {
        const int m = tid >> 2, c0 = 272 + (tid & 3) * 4;
        ushort4 z; z.x = z.y = z.z = z.w = 0;
        *reinterpret_cast<ushort4*>(&A[m * LDA + c0]) = z;
    }

    const int m = tid >> 2;             // node row 0..63
    const int q = tid & 3;              // channel quarter
    float psum[2] = {0.f, 0.f}, psq[2] = {0.f, 0.f};

    const int per   = nb * 64;
    const int iters = (n + per - 1) / per;

    for (int it = 0; it < iters; ++it) {
        const int base = (it * nb + lb) * 64;
        const int i = base + m;

        // ---- gather + bf16 pack ----
        if (i < n) {
            const int* ar = aidx + (size_t)i * (deg + 1);
            const int own = ar[0];
            if (q == 0) own_lds[m] = own;
            unsigned short* row = A + m * LDA;

            const float4* sp = (const float4*)(atom + (size_t)own * 128) + q * 8;
            float4 s0 = sp[0], s1 = sp[1], s2 = sp[2], s3 = sp[3],
                   s4 = sp[4], s5 = sp[5], s6 = sp[6], s7 = sp[7];
            // self -> cols 144 + 32q ..
            unsigned short* ps = row + 144 + q * 32;
            st_bf4(ps +  0, s0); st_bf4(ps +  4, s1); st_bf4(ps +  8, s2); st_bf4(ps + 12, s3);
            st_bf4(ps + 16, s4); st_bf4(ps + 20, s5); st_bf4(ps + 24, s6); st_bf4(ps + 28, s7);
            // + neighbors
            for (int j = 1; j <= deg; ++j) {
                const float4* p = (const float4*)(atom + (size_t)ar[j] * 128) + q * 8;
                s0 = add4(s0, p[0]); s1 = add4(s1, p[1]); s2 = add4(s2, p[2]); s3 = add4(s3, p[3]);
                s4 = add4(s4, p[4]); s5 = add4(s5, p[5]); s6 = add4(s6, p[6]); s7 = add4(s7, p[7]);
            }
            unsigned short* pa = row + q * 32;
            st_bf4(pa +  0, s0); st_bf4(pa +  4, s1); st_bf4(pa +  8, s2); st_bf4(pa + 12, s3);
            st_bf4(pa + 16, s4); st_bf4(pa + 20, s5); st_bf4(pa + 24, s6); st_bf4(pa + 28, s7);
            // bonds -> cols 128..143 (one thread per node)
            if (q == 1) {
                const int* br = bidx + (size_t)i * deg;
                float4 t0 = make_float4(0,0,0,0), t1 = t0, t2 = t0, t3 = t0;
                for (int j = 0; j < deg; ++j) {
                    const float4* bp = (const float4*)(bond + (size_t)br[j] * 16);
                    t0 = add4(t0, bp[0]); t1 = add4(t1, bp[1]);
                    t2 = add4(t2, bp[2]); t3 = add4(t3, bp[3]);
                }
                unsigned short* pb = row + 128;
                st_bf4(pb + 0, t0); st_bf4(pb + 4, t1); st_bf4(pb + 8, t2); st_bf4(pb + 12, t3);
            }
        }
        __syncthreads();

        // ---- MFMA: 64x288 @ 288x128 ----
        floatx4 acc[4][2];
        #pragma unroll
        for (int mt = 0; mt < 4; ++mt)
            #pragma unroll
            for (int nt = 0; nt < 2; ++nt)
                acc[mt][nt] = (floatx4){0.f, 0.f, 0.f, 0.f};

        #pragma unroll
        for (int ks = 0; ks < 9; ++ks) {
            short8 af[4];
            #pragma unroll
            for (int mt = 0; mt < 4; ++mt)
                af[mt] = *(const short8*)&A[(mt * 16 + lrow) * LDA + ks * 32 + (lkhi << 3)];
            #pragma unroll
            for (int mt = 0; mt < 4; ++mt) {
                acc[mt][0] = __builtin_amdgcn_mfma_f32_16x16x32_bf16(af[mt], bfr[ks][0], acc[mt][0], 0, 0, 0);
                acc[mt][1] = __builtin_amdgcn_mfma_f32_16x16x32_bf16(af[mt], bfr[ks][1], acc[mt][1], 0, 0, 0);
            }
        }

        // ---- scatter + BN partials (masked to valid rows) ----
        #pragma unroll
        for (int mt = 0; mt < 4; ++mt) {
            #pragma unroll
            for (int r = 0; r < 4; ++r) {
                const int row = mt * 16 + (lkhi << 2) + r;
                const int gi = base + row;
                if (gi < n) {
                    const int o = own_lds[row];
                    #pragma unroll
                    for (int nt = 0; nt < 2; ++nt) {
                        const float v = acc[mt][nt][r] + bias_r[nt];
                        out[(size_t)o * 128 + nbase + nt * 16 + lrow] = v;
                        psum[nt] += v;
                        psq[nt]  += v * v;
                    }
                }
            }
        }
        __syncthreads();
    }

    // ---- deterministic per-block channel partials ----
    #pragma unroll
    for (int nt = 0; nt < 2; ++nt) {
        float s = psum[nt], sq = psq[nt];
        s  += __shfl_xor(s, 16, 64);  s  += __shfl_xor(s, 32, 64);
        sq += __shfl_xor(sq, 16, 64); sq += __shfl_xor(sq, 32, 64);
        if (lane < 16) {
            sumPart[(size_t)blk * 128 + nbase + nt * 16 + lane] = s;
            sqPart [(size_t)blk * 128 + nbase + nt * 16 + lane] = sq;
        }
    }
}

// ---------------------------------------------------------------------------
// Reduce TOTB partials per channel -> mean, invstd (deterministic).
// ---------------------------------------------------------------------------
__global__ void gdc_stats(const float* __restrict__ sumPart,
                          const float* __restrict__ sqPart,
                          float* __restrict__ mv)
{
    const int c = blockIdx.x;
    const int j = threadIdx.x;
    __shared__ float rs[256], rq[256];
    float s = 0.f, q = 0.f;
    for (int b = j; b < TOTB; b += 256) {
        s += sumPart[(size_t)b * 128 + c];
        q += sqPart[(size_t)b * 128 + c];
    }
    rs[j] = s; rq[j] = q;
    __syncthreads();
    for (int off = 128; off > 0; off >>= 1) {
        if (j < off) { rs[j] += rs[j + off]; rq[j] += rq[j + off]; }
        __syncthreads();
    }
    if (j == 0) {
        const float mean = rs[0] / (float)N_ATOMS;
        const float var  = rq[0] / (float)N_ATOMS - mean * mean;
        mv[c]       = mean;
        mv[128 + c] = rsqrtf(var + EPS);
    }
}

// ---------------------------------------------------------------------------
// In-place normalize + ReLU. float4; per-thread channel loop-invariant.
// ---------------------------------------------------------------------------
__global__ __launch_bounds__(256) void gdc_norm(float* __restrict__ out,
                                                const float* __restrict__ mv)
{
    const size_t total4 = (size_t)N_ATOMS * 128 / 4;
    size_t idx = (size_t)blockIdx.x * 256 + threadIdx.x;
    const int c = (int)((idx * 4) & 127);
    const float4 m  = *(const float4*)(mv + c);
    const float4 iv = *(const float4*)(mv + 128 + c);
    const size_t stride = (size_t)gridDim.x * 256;
    for (; idx < total4; idx += stride) {
        float4 v = ((float4*)out)[idx];
        v.x = fmaxf(0.f, (v.x - m.x) * iv.x);
        v.y = fmaxf(0.f, (v.y - m.y) * iv.y);
        v.z = fmaxf(0.f, (v.z - m.z) * iv.z);
        v.w = fmaxf(0.f, (v.w - m.w) * iv.w);
        ((float4*)out)[idx] = v;
    }
}

extern "C" void kernel_launch(void* const* d_in, const int* in_sizes, int n_in,
                              void* d_out, int out_size, void* d_ws, size_t ws_size,
                              hipStream_t stream) {
    const float* atom  = (const float*)d_in[0];
    const float* bond  = (const float*)d_in[1];
    const int*   a1    = (const int*)d_in[2];
    const int*   b1    = (const int*)d_in[3];
    const int*   a2    = (const int*)d_in[4];
    const int*   b2    = (const int*)d_in[5];
    const int*   a3    = (const int*)d_in[6];
    const int*   b3    = (const int*)d_in[7];
    const int*   a4    = (const int*)d_in[8];
    const int*   b4    = (const int*)d_in[9];
    const float* Wself = (const float*)d_in[10];
    const float* W1    = (const float*)d_in[11];
    const float* W2    = (const float*)d_in[12];
    const float* W3    = (const float*)d_in[13];
    const float* W4    = (const float*)d_in[14];
    const float* bias  = (const float*)d_in[15];
    float* out = (float*)d_out;

    // ws layout: sumPart[TOTB*128] | sqPart[TOTB*128] | mv[256]
    float* sumPart = (float*)d_ws;
    float* sqPart  = sumPart + (size_t)TOTB * 128;
    float* mv      = sqPart + (size_t)TOTB * 128;

    hipLaunchKernelGGL(gdc_mfma, dim3(TOTB), dim3(256), 0, stream,
                       atom, bond, a1, b1, a2, b2, a3, b3, a4, b4,
                       W1, W2, W3, W4, Wself, bias, out, sumPart, sqPart);
    hipLaunchKernelGGL(gdc_stats, dim3(128), dim3(256), 0, stream,
                       sumPart, sqPart, mv);
    hipLaunchKernelGGL(gdc_norm, dim3(2048), dim3(256), 0, stream, out, mv);
}

// Round 3
// 425.362 us; speedup vs baseline: 8.1479x; 1.1117x over previous
//
#include <hip/hip_runtime.h>
#include <hip/hip_bf16.h>
#include <math.h>

#define N_ATOMS 500000
#define EPS 1e-5f
#define LDA 296   // bf16 elems per A_lds row: 288 + 8 pad

// blocks per degree segment, ~proportional to gather volume n_d*(d+1)
#define NB1 105
#define NB2 472
#define NB3 839
#define NB4 524
#define TOTB (NB1 + NB2 + NB3 + NB4)   // 1940

#define SEG_ELEMS 36864   // 288*128 bf16 per packed segment

typedef __attribute__((ext_vector_type(8))) short short8;
typedef __attribute__((ext_vector_type(4))) float floatx4;

__device__ __forceinline__ unsigned short f2bf(float f) {
    unsigned int x = __float_as_uint(f);
    x += 0x7FFF + ((x >> 16) & 1);          // round-to-nearest-even
    return (unsigned short)(x >> 16);
}

__device__ __forceinline__ float4 add4(float4 a, float4 b) {
    return make_float4(a.x + b.x, a.y + b.y, a.z + b.z, a.w + b.w);
}

__device__ __forceinline__ void st_bf4(unsigned short* p, float4 v) {
    ushort4 u;
    u.x = f2bf(v.x); u.y = f2bf(v.y); u.z = f2bf(v.z); u.w = f2bf(v.w);
    *reinterpret_cast<ushort4*>(p) = u;     // ds_write_b64
}

// ---------------------------------------------------------------------------
// Pack weights into MFMA B-fragment layout, bf16.
// packed[d] : for ks(9), nt(8), lane(64) -> short8 of col nt*16+(lane&15),
//             k = ks*32 + (lane>>4)*8 + j,  [W_d rows 0..143 | W_self 144..271 | 0]
// 4*9*8*64 = 18432 threads.
// ---------------------------------------------------------------------------
__global__ __launch_bounds__(256) void gdc_pack(
    const float* __restrict__ W1, const float* __restrict__ W2,
    const float* __restrict__ W3, const float* __restrict__ W4,
    const float* __restrict__ Wself, unsigned short* __restrict__ packed)
{
    const int t = blockIdx.x * 256 + threadIdx.x;
    if (t >= 4 * 9 * 8 * 64) return;
    const int d    = t / 4608;          // 0..3 -> degree d+1
    const int r    = t % 4608;
    const int ks   = r / 512;
    const int nt   = (r % 512) / 64;
    const int lane = r % 64;
    const float* Wd = (d == 0) ? W1 : (d == 1) ? W2 : (d == 2) ? W3 : W4;
    const int col = nt * 16 + (lane & 15);
    short8 v;
    #pragma unroll
    for (int j = 0; j < 8; ++j) {
        const int k = ks * 32 + ((lane >> 4) << 3) + j;
        float w = 0.f;
        if (k < 144)      w = Wd[k * 128 + col];
        else if (k < 272) w = Wself[(k - 144) * 128 + col];
        v[j] = (short)f2bf(w);
    }
    *reinterpret_cast<short8*>(packed + (size_t)d * SEG_ELEMS
                               + ((size_t)(ks * 8 + nt) * 64 + lane) * 8) = v;
}

// ---------------------------------------------------------------------------
// Fused: gather -> bf16 pack -> MFMA (64x288 @ 288x128) -> scatter + BN partials
// 256 threads = 4 waves; wave w owns output cols [32w, 32w+32).
// ---------------------------------------------------------------------------
__global__ __launch_bounds__(256, 4) void gdc_mfma(
    const float* __restrict__ atom, const float* __restrict__ bond,
    const int* __restrict__ a1, const int* __restrict__ b1,
    const int* __restrict__ a2, const int* __restrict__ b2,
    const int* __restrict__ a3, const int* __restrict__ b3,
    const int* __restrict__ a4, const int* __restrict__ b4,
    const unsigned short* __restrict__ packedW, const float* __restrict__ bias,
    float* __restrict__ out,
    float* __restrict__ sumPart, float* __restrict__ sqPart)
{
    __shared__ __align__(16) unsigned short A[64 * LDA];   // 37888 B
    __shared__ int own_lds[64];

    const int blk = blockIdx.x;
    int deg, n, lb, nb;
    const int* aidx; const int* bidx;
    if (blk < NB1)                 { deg = 1; n =  50000; lb = blk;                  nb = NB1; aidx = a1; bidx = b1; }
    else if (blk < NB1+NB2)        { deg = 2; n = 150000; lb = blk-NB1;              nb = NB2; aidx = a2; bidx = b2; }
    else if (blk < NB1+NB2+NB3)    { deg = 3; n = 200000; lb = blk-(NB1+NB2);        nb = NB3; aidx = a3; bidx = b3; }
    else                           { deg = 4; n = 100000; lb = blk-(NB1+NB2+NB3);    nb = NB4; aidx = a4; bidx = b4; }

    const int tid  = threadIdx.x;
    const int lane = tid & 63;
    const int wv   = tid >> 6;          // 0..3
    const int nbase = wv * 32;
    const int lrow  = lane & 15;
    const int lkhi  = lane >> 4;

    // ---- B fragments: 18 coalesced 16B loads from packed layout ----
    short8 bfr[9][2];
    {
        const short8* pw = (const short8*)(packedW + (size_t)(deg - 1) * SEG_ELEMS);
        #pragma unroll
        for (int ks = 0; ks < 9; ++ks) {
            bfr[ks][0] = pw[(ks * 8 + wv * 2) * 64 + lane];
            bfr[ks][1] = pw[(ks * 8 + wv * 2 + 1) * 64 + lane];
        }
    }
    float bias_r[2];
    bias_r[0] = bias[nbase + lrow];
    bias_r[1] = bias[nbase + 16 + lrow];

    // zero K-pad cols 272..287 (stays zero forever)
    {
        const int m0 = tid >> 2, c0 = 272 + (tid & 3) * 4;
        ushort4 z; z.x = z.y = z.z = z.w = 0;
        *reinterpret_cast<ushort4*>(&A[m0 * LDA + c0]) = z;
    }

    const int m = tid >> 2;             // node row 0..63
    const int q = tid & 3;              // channel quarter
    float psum[2] = {0.f, 0.f}, psq[2] = {0.f, 0.f};

    const int per   = nb * 64;
    const int iters = (n + per - 1) / per;

    for (int it = 0; it < iters; ++it) {
        const int base = (it * nb + lb) * 64;
        const int i = base + m;

        if (i < n) {
            const int* ar = aidx + (size_t)i * (deg + 1);
            const int own = ar[0];
            if (q == 0) own_lds[m] = own;
            unsigned short* row = A + m * LDA;

            const float4* sp = (const float4*)(atom + (size_t)own * 128) + q * 8;
            float4 s0 = sp[0], s1 = sp[1], s2 = sp[2], s3 = sp[3],
                   s4 = sp[4], s5 = sp[5], s6 = sp[6], s7 = sp[7];
            unsigned short* ps = row + 144 + q * 32;
            st_bf4(ps +  0, s0); st_bf4(ps +  4, s1); st_bf4(ps +  8, s2); st_bf4(ps + 12, s3);
            st_bf4(ps + 16, s4); st_bf4(ps + 20, s5); st_bf4(ps + 24, s6); st_bf4(ps + 28, s7);
            for (int j = 1; j <= deg; ++j) {
                const float4* p = (const float4*)(atom + (size_t)ar[j] * 128) + q * 8;
                s0 = add4(s0, p[0]); s1 = add4(s1, p[1]); s2 = add4(s2, p[2]); s3 = add4(s3, p[3]);
                s4 = add4(s4, p[4]); s5 = add4(s5, p[5]); s6 = add4(s6, p[6]); s7 = add4(s7, p[7]);
            }
            unsigned short* pa = row + q * 32;
            st_bf4(pa +  0, s0); st_bf4(pa +  4, s1); st_bf4(pa +  8, s2); st_bf4(pa + 12, s3);
            st_bf4(pa + 16, s4); st_bf4(pa + 20, s5); st_bf4(pa + 24, s6); st_bf4(pa + 28, s7);
            if (q == 1) {
                const int* br = bidx + (size_t)i * deg;
                float4 t0 = make_float4(0,0,0,0), t1 = t0, t2 = t0, t3 = t0;
                for (int j = 0; j < deg; ++j) {
                    const float4* bp = (const float4*)(bond + (size_t)br[j] * 16);
                    t0 = add4(t0, bp[0]); t1 = add4(t1, bp[1]);
                    t2 = add4(t2, bp[2]); t3 = add4(t3, bp[3]);
                }
                unsigned short* pb = row + 128;
                st_bf4(pb + 0, t0); st_bf4(pb + 4, t1); st_bf4(pb + 8, t2); st_bf4(pb + 12, t3);
            }
        }
        __syncthreads();

        floatx4 acc[4][2];
        #pragma unroll
        for (int mt = 0; mt < 4; ++mt)
            #pragma unroll
            for (int nt = 0; nt < 2; ++nt)
                acc[mt][nt] = (floatx4){0.f, 0.f, 0.f, 0.f};

        #pragma unroll
        for (int ks = 0; ks < 9; ++ks) {
            short8 af[4];
            #pragma unroll
            for (int mt = 0; mt < 4; ++mt)
                af[mt] = *(const short8*)&A[(mt * 16 + lrow) * LDA + ks * 32 + (lkhi << 3)];
            #pragma unroll
            for (int mt = 0; mt < 4; ++mt) {
                acc[mt][0] = __builtin_amdgcn_mfma_f32_16x16x32_bf16(af[mt], bfr[ks][0], acc[mt][0], 0, 0, 0);
                acc[mt][1] = __builtin_amdgcn_mfma_f32_16x16x32_bf16(af[mt], bfr[ks][1], acc[mt][1], 0, 0, 0);
            }
        }

        #pragma unroll
        for (int mt = 0; mt < 4; ++mt) {
            #pragma unroll
            for (int r = 0; r < 4; ++r) {
                const int row = mt * 16 + (lkhi << 2) + r;
                const int gi = base + row;
                if (gi < n) {
                    const int o = own_lds[row];
                    #pragma unroll
                    for (int nt = 0; nt < 2; ++nt) {
                        const float v = acc[mt][nt][r] + bias_r[nt];
                        out[(size_t)o * 128 + nbase + nt * 16 + lrow] = v;
                        psum[nt] += v;
                        psq[nt]  += v * v;
                    }
                }
            }
        }
        __syncthreads();
    }

    #pragma unroll
    for (int nt = 0; nt < 2; ++nt) {
        float s = psum[nt], sq = psq[nt];
        s  += __shfl_xor(s, 16, 64);  s  += __shfl_xor(s, 32, 64);
        sq += __shfl_xor(sq, 16, 64); sq += __shfl_xor(sq, 32, 64);
        if (lane < 16) {
            sumPart[(size_t)blk * 128 + nbase + nt * 16 + lane] = s;
            sqPart [(size_t)blk * 128 + nbase + nt * 16 + lane] = sq;
        }
    }
}

// ---------------------------------------------------------------------------
// Reduce TOTB partials per channel -> mean, invstd (deterministic).
// ---------------------------------------------------------------------------
__global__ void gdc_stats(const float* __restrict__ sumPart,
                          const float* __restrict__ sqPart,
                          float* __restrict__ mv)
{
    const int c = blockIdx.x;
    const int j = threadIdx.x;
    __shared__ float rs[256], rq[256];
    float s = 0.f, q = 0.f;
    for (int b = j; b < TOTB; b += 256) {
        s += sumPart[(size_t)b * 128 + c];
        q += sqPart[(size_t)b * 128 + c];
    }
    rs[j] = s; rq[j] = q;
    __syncthreads();
    for (int off = 128; off > 0; off >>= 1) {
        if (j < off) { rs[j] += rs[j + off]; rq[j] += rq[j + off]; }
        __syncthreads();
    }
    if (j == 0) {
        const float mean = rs[0] / (float)N_ATOMS;
        const float var  = rq[0] / (float)N_ATOMS - mean * mean;
        mv[c]       = mean;
        mv[128 + c] = rsqrtf(var + EPS);
    }
}

// ---------------------------------------------------------------------------
// In-place normalize + ReLU. float4; per-thread channel loop-invariant.
// ---------------------------------------------------------------------------
__global__ __launch_bounds__(256) void gdc_norm(float* __restrict__ out,
                                                const float* __restrict__ mv)
{
    const size_t total4 = (size_t)N_ATOMS * 128 / 4;
    size_t idx = (size_t)blockIdx.x * 256 + threadIdx.x;
    const int c = (int)((idx * 4) & 127);
    const float4 m  = *(const float4*)(mv + c);
    const float4 iv = *(const float4*)(mv + 128 + c);
    const size_t stride = (size_t)gridDim.x * 256;
    for (; idx < total4; idx += stride) {
        float4 v = ((float4*)out)[idx];
        v.x = fmaxf(0.f, (v.x - m.x) * iv.x);
        v.y = fmaxf(0.f, (v.y - m.y) * iv.y);
        v.z = fmaxf(0.f, (v.z - m.z) * iv.z);
        v.w = fmaxf(0.f, (v.w - m.w) * iv.w);
        ((float4*)out)[idx] = v;
    }
}

extern "C" void kernel_launch(void* const* d_in, const int* in_sizes, int n_in,
                              void* d_out, int out_size, void* d_ws, size_t ws_size,
                              hipStream_t stream) {
    const float* atom  = (const float*)d_in[0];
    const float* bond  = (const float*)d_in[1];
    const int*   a1    = (const int*)d_in[2];
    const int*   b1    = (const int*)d_in[3];
    const int*   a2    = (const int*)d_in[4];
    const int*   b2    = (const int*)d_in[5];
    const int*   a3    = (const int*)d_in[6];
    const int*   b3    = (const int*)d_in[7];
    const int*   a4    = (const int*)d_in[8];
    const int*   b4    = (const int*)d_in[9];
    const float* Wself = (const float*)d_in[10];
    const float* W1    = (const float*)d_in[11];
    const float* W2    = (const float*)d_in[12];
    const float* W3    = (const float*)d_in[13];
    const float* W4    = (const float*)d_in[14];
    const float* bias  = (const float*)d_in[15];
    float* out = (float*)d_out;

    // ws layout: packedW (4*36864 bf16 = 294912 B) | sumPart | sqPart | mv
    unsigned short* packedW = (unsigned short*)d_ws;
    float* sumPart = (float*)((char*)d_ws + 4 * SEG_ELEMS * sizeof(unsigned short));
    float* sqPart  = sumPart + (size_t)TOTB * 128;
    float* mv      = sqPart + (size_t)TOTB * 128;

    hipLaunchKernelGGL(gdc_pack, dim3((4*9*8*64 + 255)/256), dim3(256), 0, stream,
                       W1, W2, W3, W4, Wself, packedW);
    hipLaunchKernelGGL(gdc_mfma, dim3(TOTB), dim3(256), 0, stream,
                       atom, bond, a1, b1, a2, b2, a3, b3, a4, b4,
                       packedW, bias, out, sumPart, sqPart);
    hipLaunchKernelGGL(gdc_stats, dim3(128), dim3(256), 0, stream,
                       sumPart, sqPart, mv);
    hipLaunchKernelGGL(gdc_norm, dim3(2048), dim3(256), 0, stream, out, mv);
}